// Round 1
// baseline (95.774 us; speedup 1.0000x reference)
//
#include <hip/hip_runtime.h>
#include <stdint.h>
#include <math.h>

// ---------------------------------------------------------------------------
// Sampler: temperature-scale -> top-k threshold -> Gumbel-max categorical
// Exact reproduction of the JAX reference, including Threefry-2x32 PRNG.
//
// PRNG_MODE selects the hypothesis for jax's threefry_random_bits layout:
//   0: partitionable, bits = out0 ^ out1   (counter = (0, j))   [best guess]
//   1: partitionable, bits = out0
//   2: partitionable, bits = out1
//   3: legacy (non-partitionable): counters split in halves,
//      j < n/2 -> out0 of (j, j+n/2); j >= n/2 -> out1 of (j-n/2, j)
// ---------------------------------------------------------------------------
#define PRNG_MODE 0

#define BLOCK 1024
#define NBIN  4096
#define CAP   4096

__device__ __forceinline__ uint32_t rotl32(uint32_t x, uint32_t r) {
  return (x << r) | (x >> (32u - r));
}

// order-preserving map f32 -> u32 (ascending float => ascending key)
__device__ __forceinline__ uint32_t f2key(float x) {
  uint32_t b = __float_as_uint(x);
  return (b & 0x80000000u) ? ~b : (b | 0x80000000u);
}

// Threefry-2x32, 20 rounds, key = (0, 42)  [jax.random.key(42)]
__device__ __forceinline__ void tf2x32(uint32_t x0, uint32_t x1,
                                       uint32_t &o0, uint32_t &o1) {
  const uint32_t k0 = 0u, k1 = 42u;
  const uint32_t k2 = k0 ^ k1 ^ 0x1BD11BDAu;
  x0 += k0; x1 += k1;
#define TF_R(r) { x0 += x1; x1 = rotl32(x1, (r)); x1 ^= x0; }
  TF_R(13u) TF_R(15u) TF_R(26u) TF_R(6u)
  x0 += k1; x1 += k2 + 1u;
  TF_R(17u) TF_R(29u) TF_R(16u) TF_R(24u)
  x0 += k2; x1 += k0 + 2u;
  TF_R(13u) TF_R(15u) TF_R(26u) TF_R(6u)
  x0 += k0; x1 += k1 + 3u;
  TF_R(17u) TF_R(29u) TF_R(16u) TF_R(24u)
  x0 += k1; x1 += k2 + 4u;
  TF_R(13u) TF_R(15u) TF_R(26u) TF_R(6u)
  x0 += k2; x1 += k0 + 5u;
#undef TF_R
  o0 = x0; o1 = x1;
}

__device__ __forceinline__ uint32_t random_bits_at(uint32_t j, uint32_t half) {
  uint32_t o0, o1;
#if PRNG_MODE == 3
  if (j < half) { tf2x32(j, j + half, o0, o1); return o0; }
  else          { tf2x32(j - half, j, o0, o1); return o1; }
#else
  (void)half;
  tf2x32(0u, j, o0, o1);  // counter = uint64(j): hi = 0, lo = j
#if PRNG_MODE == 0
  return o0 ^ o1;
#elif PRNG_MODE == 1
  return o0;
#else
  return o1;
#endif
#endif
}

// gumbel = -log(-log(u)), u = max(tiny, f*(1-tiny)+tiny), f = mantissa-uniform
__device__ __forceinline__ float gumbel_at(uint32_t j, uint32_t half) {
  uint32_t bits = random_bits_at(j, half);
  float f = __uint_as_float((bits >> 9) | 0x3F800000u) - 1.0f;
  const float TINY = 1.17549435e-38f;
  float u = (f == 0.0f) ? TINY : f;  // exact: f + tiny rounds to f for all f>0
  return -logf(-logf(u));
}

// All threads participate. Finds bin (descending scan over hist[4096]) holding
// the Kt-th largest element and the 1-based rank within that bin.
__device__ void find4096(uint32_t* hist, uint32_t* super, uint32_t Kt,
                         uint32_t* s_bin, uint32_t* s_rank) {
  const int tid = threadIdx.x;
  if (tid < 64) {
    uint32_t s = 0;
    for (int i = 0; i < 64; ++i) s += hist[tid * 64 + i];
    super[tid] = s;
  }
  __syncthreads();
  if (tid == 0) {
    uint32_t acc = 0; int sb = 0;
    for (int s = 63; s >= 0; --s) {
      if (acc + super[s] >= Kt) { sb = s; break; }
      acc += super[s];
    }
    uint32_t bfound = (uint32_t)(sb * 64);
    for (int i = 63; i >= 0; --i) {
      uint32_t bin = (uint32_t)(sb * 64 + i);
      if (acc + hist[bin] >= Kt) { bfound = bin; break; }
      acc += hist[bin];
    }
    *s_bin = bfound; *s_rank = Kt - acc;
  }
  __syncthreads();
}

__global__ __launch_bounds__(BLOCK)
void sampler_kernel(const float* __restrict__ logits,
                    const float* __restrict__ temps,
                    const int* __restrict__ topk_p,
                    int* __restrict__ out, int B, int V) {
  const int r = blockIdx.x;
  const int tid = threadIdx.x;
  const uint32_t K = (uint32_t)(*topk_p);
  const float temp = temps[r];
  const float* row = logits + (size_t)r * (size_t)V;
  const uint32_t n = (uint32_t)B * (uint32_t)V;
  const uint32_t half = n >> 1;

  __shared__ uint32_t hist[NBIN];
  __shared__ uint32_t super[64];
  __shared__ uint32_t cand[CAP];
  __shared__ uint32_t s_cnt, s_bin, s_rank, s_kth;

  const int n4 = V >> 2;
  const float4* row4 = (const float4*)row;

  // ---- pass 1: histogram of top 12 bits of sortable key ----
  for (int i = tid; i < NBIN; i += BLOCK) hist[i] = 0u;
  if (tid == 0) s_cnt = 0u;
  __syncthreads();
  for (int i = tid; i < n4; i += BLOCK) {
    float4 x = row4[i];
    atomicAdd(&hist[f2key(x.x / temp) >> 20], 1u);
    atomicAdd(&hist[f2key(x.y / temp) >> 20], 1u);
    atomicAdd(&hist[f2key(x.z / temp) >> 20], 1u);
    atomicAdd(&hist[f2key(x.w / temp) >> 20], 1u);
  }
  for (int i = (n4 << 2) + tid; i < V; i += BLOCK)
    atomicAdd(&hist[f2key(row[i] / temp) >> 20], 1u);
  __syncthreads();
  find4096(hist, super, K, &s_bin, &s_rank);
  const uint32_t b1 = s_bin;
  const uint32_t r1 = s_rank;

  // ---- pass 2: collect keys landing in bin b1 ----
  for (int i = tid; i < n4; i += BLOCK) {
    float4 x = row4[i];
    float s[4] = {x.x / temp, x.y / temp, x.z / temp, x.w / temp};
#pragma unroll
    for (int q = 0; q < 4; ++q) {
      uint32_t key = f2key(s[q]);
      if ((key >> 20) == b1) {
        uint32_t p = atomicAdd(&s_cnt, 1u);
        if (p < CAP) cand[p] = key;
      }
    }
  }
  for (int i = (n4 << 2) + tid; i < V; i += BLOCK) {
    uint32_t key = f2key(row[i] / temp);
    if ((key >> 20) == b1) {
      uint32_t p = atomicAdd(&s_cnt, 1u);
      if (p < CAP) cand[p] = key;
    }
  }
  __syncthreads();
  const uint32_t cnt = s_cnt;

  // ---- refine to the exact kth key ----
  if (cnt <= CAP) {
    // in-LDS refinement over the collected bin members
    for (int i = tid; i < NBIN; i += BLOCK) hist[i] = 0u;
    __syncthreads();
    for (int i = tid; i < (int)cnt; i += BLOCK)
      atomicAdd(&hist[(cand[i] >> 8) & 0xFFFu], 1u);
    __syncthreads();
    find4096(hist, super, r1, &s_bin, &s_rank);
    const uint32_t b2 = s_bin;
    const uint32_t r2 = s_rank;
    for (int i = tid; i < 256; i += BLOCK) hist[i] = 0u;
    __syncthreads();
    for (int i = tid; i < (int)cnt; i += BLOCK) {
      uint32_t key = cand[i];
      if (((key >> 8) & 0xFFFu) == b2) atomicAdd(&hist[key & 0xFFu], 1u);
    }
    __syncthreads();
    if (tid == 0) {
      uint32_t acc = 0; uint32_t b3 = 0;
      for (int i = 255; i >= 0; --i) {
        if (acc + hist[i] >= r2) { b3 = (uint32_t)i; break; }
        acc += hist[i];
      }
      s_kth = (b1 << 20) | (b2 << 8) | b3;
    }
    __syncthreads();
  } else {
    // fallback (duplicate-heavy pathological data): refine from global memory
    for (int i = tid; i < NBIN; i += BLOCK) hist[i] = 0u;
    __syncthreads();
    for (int i = tid; i < V; i += BLOCK) {
      uint32_t key = f2key(row[i] / temp);
      if ((key >> 20) == b1) atomicAdd(&hist[(key >> 8) & 0xFFFu], 1u);
    }
    __syncthreads();
    find4096(hist, super, r1, &s_bin, &s_rank);
    const uint32_t b2 = s_bin;
    const uint32_t r2 = s_rank;
    for (int i = tid; i < 256; i += BLOCK) hist[i] = 0u;
    __syncthreads();
    for (int i = tid; i < V; i += BLOCK) {
      uint32_t key = f2key(row[i] / temp);
      if ((key >> 8) == ((b1 << 12) | b2)) atomicAdd(&hist[key & 0xFFu], 1u);
    }
    __syncthreads();
    if (tid == 0) {
      uint32_t acc = 0; uint32_t b3 = 0;
      for (int i = 255; i >= 0; --i) {
        if (acc + hist[i] >= r2) { b3 = (uint32_t)i; break; }
        acc += hist[i];
      }
      s_kth = (b1 << 20) | (b2 << 8) | b3;
    }
    __syncthreads();
  }
  const uint32_t kth_key = s_kth;

  // ---- final pass: gumbel-argmax over kept entries (key >= kth) ----
  float bv = -INFINITY;
  int bi = 0x7FFFFFFF;
  for (int i = tid; i < n4; i += BLOCK) {
    float4 x = row4[i];
    float s[4] = {x.x / temp, x.y / temp, x.z / temp, x.w / temp};
#pragma unroll
    for (int q = 0; q < 4; ++q) {
      uint32_t key = f2key(s[q]);
      if (key >= kth_key) {
        int v = (i << 2) + q;
        float g = gumbel_at((uint32_t)r * (uint32_t)V + (uint32_t)v, half);
        float val = s[q] + g;
        if (val > bv || (val == bv && v < bi)) { bv = val; bi = v; }
      }
    }
  }
  for (int i = (n4 << 2) + tid; i < V; i += BLOCK) {
    float sc = row[i] / temp;
    uint32_t key = f2key(sc);
    if (key >= kth_key) {
      float g = gumbel_at((uint32_t)r * (uint32_t)V + (uint32_t)i, half);
      float val = sc + g;
      if (val > bv || (val == bv && i < bi)) { bv = val; bi = i; }
    }
  }
  __syncthreads();  // hist reuse below
  float* rv = (float*)hist;           // 1024 floats
  int*   ri = (int*)(hist + BLOCK);   // 1024 ints
  rv[tid] = bv; ri[tid] = bi;
  __syncthreads();
  for (int s = BLOCK >> 1; s > 0; s >>= 1) {
    if (tid < s) {
      float ov = rv[tid + s]; int oi = ri[tid + s];
      if (ov > rv[tid] || (ov == rv[tid] && oi < ri[tid])) {
        rv[tid] = ov; ri[tid] = oi;
      }
    }
    __syncthreads();
  }
  if (tid == 0) out[r] = ri[0];
}

extern "C" void kernel_launch(void* const* d_in, const int* in_sizes, int n_in,
                              void* d_out, int out_size, void* d_ws, size_t ws_size,
                              hipStream_t stream) {
  const float* logits = (const float*)d_in[0];
  const float* temps  = (const float*)d_in[1];
  const int*   topk   = (const int*)d_in[2];
  int* out = (int*)d_out;
  const int B = in_sizes[1];           // 256
  const int V = in_sizes[0] / B;       // 128000
  sampler_kernel<<<B, BLOCK, 0, stream>>>(logits, temps, topk, out, B, V);
}

// Round 2
// 70.423 us; speedup vs baseline: 1.3600x; 1.3600x over previous
//
#include <hip/hip_runtime.h>
#include <stdint.h>
#include <math.h>

// ---------------------------------------------------------------------------
// Sampler: temperature-scale -> top-k threshold -> Gumbel-max categorical.
// Exact reproduction of the JAX reference (threefry partitionable, key 42).
//
// R1 structure: top-k selection runs on RAW logit bits (division is monotone,
// so kth scaled == kth logit / temp). Pass 1: 4096-bin histogram of key>>20.
// Pass 2: collect (key,idx) of all elements with key >= binfloor-64ulp (the
// full top-k superset, ~K + bin population). Then: exact kth via in-LDS
// refinement, exact scaled>=kth_scaled filter (division only on candidates),
// gumbel + argmax over candidates in LDS. No third global pass.
// ---------------------------------------------------------------------------

#define BLOCK 1024
#define NBIN  4096
#define CAP   4096
#define SLACK 64u

__device__ __forceinline__ uint32_t rotl32(uint32_t x, uint32_t r) {
  return (x << r) | (x >> (32u - r));
}

// order-preserving map f32 -> u32
__device__ __forceinline__ uint32_t f2key(float x) {
  uint32_t b = __float_as_uint(x);
  return (b & 0x80000000u) ? ~b : (b | 0x80000000u);
}
__device__ __forceinline__ float key2f(uint32_t k) {
  uint32_t b = (k & 0x80000000u) ? (k & 0x7FFFFFFFu) : ~k;
  return __uint_as_float(b);
}

// Threefry-2x32, key = (0, 42)
__device__ __forceinline__ void tf2x32(uint32_t x0, uint32_t x1,
                                       uint32_t &o0, uint32_t &o1) {
  const uint32_t k0 = 0u, k1 = 42u;
  const uint32_t k2 = k0 ^ k1 ^ 0x1BD11BDAu;
  x0 += k0; x1 += k1;
#define TF_R(r) { x0 += x1; x1 = rotl32(x1, (r)); x1 ^= x0; }
  TF_R(13u) TF_R(15u) TF_R(26u) TF_R(6u)
  x0 += k1; x1 += k2 + 1u;
  TF_R(17u) TF_R(29u) TF_R(16u) TF_R(24u)
  x0 += k2; x1 += k0 + 2u;
  TF_R(13u) TF_R(15u) TF_R(26u) TF_R(6u)
  x0 += k0; x1 += k1 + 3u;
  TF_R(17u) TF_R(29u) TF_R(16u) TF_R(24u)
  x0 += k1; x1 += k2 + 4u;
  TF_R(13u) TF_R(15u) TF_R(26u) TF_R(6u)
  x0 += k2; x1 += k0 + 5u;
#undef TF_R
  o0 = x0; o1 = x1;
}

__device__ __forceinline__ float gumbel_at(uint32_t j) {
  uint32_t o0, o1;
  tf2x32(0u, j, o0, o1);
  uint32_t bits = o0 ^ o1;
  float f = __uint_as_float((bits >> 9) | 0x3F800000u) - 1.0f;
  const float TINY = 1.17549435e-38f;
  float u = (f == 0.0f) ? TINY : f;
  return -logf(-logf(u));
}

// descending-rank select over hist[4096]; writes bin and 1-based in-bin rank
__device__ void find4096(uint32_t* hist, uint32_t* super, uint32_t Kt,
                         uint32_t* s_bin, uint32_t* s_rank) {
  const int tid = threadIdx.x;
  if (tid < 64) {
    uint32_t s = 0;
    for (int i = 0; i < 64; ++i) s += hist[tid * 64 + i];
    super[tid] = s;
  }
  __syncthreads();
  if (tid == 0) {
    uint32_t acc = 0; int sb = 0;
    for (int s = 63; s >= 0; --s) {
      if (acc + super[s] >= Kt) { sb = s; break; }
      acc += super[s];
    }
    uint32_t bfound = (uint32_t)(sb * 64);
    for (int i = 63; i >= 0; --i) {
      uint32_t bin = (uint32_t)(sb * 64 + i);
      if (acc + hist[bin] >= Kt) { bfound = bin; break; }
      acc += hist[bin];
    }
    *s_bin = bfound; *s_rank = Kt - acc;
  }
  __syncthreads();
}

__global__ __launch_bounds__(BLOCK)
void sampler_kernel(const float* __restrict__ logits,
                    const float* __restrict__ temps,
                    const int* __restrict__ topk_p,
                    int* __restrict__ out, int B, int V) {
  const int r = blockIdx.x;
  const int tid = threadIdx.x;
  const uint32_t K = (uint32_t)(*topk_p);
  const float temp = temps[r];
  const float* row = logits + (size_t)r * (size_t)V;

  __shared__ uint32_t hist[NBIN];
  __shared__ uint32_t super[64];
  __shared__ uint32_t cand_key[CAP];
  __shared__ int      cand_idx[CAP];
  __shared__ uint32_t s_cnt, s_bin, s_rank, s_kth;
  __shared__ float    s_kth_scaled;

  const int n4 = V >> 2;
  const float4* row4 = (const float4*)row;

  // ---- pass 1: histogram of raw-logit key top-12 bits (no division) ----
  for (int i = tid; i < NBIN; i += BLOCK) hist[i] = 0u;
  if (tid == 0) s_cnt = 0u;
  __syncthreads();
  for (int i = tid; i < n4; i += BLOCK) {
    float4 x = row4[i];
    atomicAdd(&hist[f2key(x.x) >> 20], 1u);
    atomicAdd(&hist[f2key(x.y) >> 20], 1u);
    atomicAdd(&hist[f2key(x.z) >> 20], 1u);
    atomicAdd(&hist[f2key(x.w) >> 20], 1u);
  }
  for (int i = (n4 << 2) + tid; i < V; i += BLOCK)
    atomicAdd(&hist[f2key(row[i]) >> 20], 1u);
  __syncthreads();
  find4096(hist, super, K, &s_bin, &s_rank);
  const uint32_t b1 = s_bin;
  const uint32_t r1 = s_rank;

  // ---- pass 2: collect (key, idx) for key >= binfloor - slack ----
  uint32_t lo = b1 << 20;
  lo = (lo >= SLACK) ? (lo - SLACK) : 0u;
  for (int i = tid; i < n4; i += BLOCK) {
    float4 x = row4[i];
    float s[4] = {x.x, x.y, x.z, x.w};
#pragma unroll
    for (int q = 0; q < 4; ++q) {
      uint32_t key = f2key(s[q]);
      if (key >= lo) {
        uint32_t p = atomicAdd(&s_cnt, 1u);
        if (p < CAP) { cand_key[p] = key; cand_idx[p] = (i << 2) + q; }
      }
    }
  }
  for (int i = (n4 << 2) + tid; i < V; i += BLOCK) {
    uint32_t key = f2key(row[i]);
    if (key >= lo) {
      uint32_t p = atomicAdd(&s_cnt, 1u);
      if (p < CAP) { cand_key[p] = key; cand_idx[p] = i; }
    }
  }
  __syncthreads();
  const uint32_t cnt = s_cnt;

  if (cnt <= CAP) {
    // ---- exact kth logit key among candidates: 3-level LDS refinement ----
    for (int i = tid; i < NBIN; i += BLOCK) hist[i] = 0u;
    __syncthreads();
    for (int i = tid; i < (int)cnt; i += BLOCK)
      atomicAdd(&hist[cand_key[i] >> 20], 1u);
    __syncthreads();
    find4096(hist, super, K, &s_bin, &s_rank);
    const uint32_t bA = s_bin; const uint32_t rA = s_rank;

    for (int i = tid; i < NBIN; i += BLOCK) hist[i] = 0u;
    __syncthreads();
    for (int i = tid; i < (int)cnt; i += BLOCK) {
      uint32_t key = cand_key[i];
      if ((key >> 20) == bA) atomicAdd(&hist[(key >> 8) & 0xFFFu], 1u);
    }
    __syncthreads();
    find4096(hist, super, rA, &s_bin, &s_rank);
    const uint32_t bB = s_bin; const uint32_t rB = s_rank;

    for (int i = tid; i < 256; i += BLOCK) hist[i] = 0u;
    __syncthreads();
    for (int i = tid; i < (int)cnt; i += BLOCK) {
      uint32_t key = cand_key[i];
      if ((key >> 8) == ((bA << 12) | bB)) atomicAdd(&hist[key & 0xFFu], 1u);
    }
    __syncthreads();
    if (tid == 0) {
      uint32_t acc = 0; uint32_t b3 = 0;
      for (int i = 255; i >= 0; --i) {
        if (acc + hist[i] >= rB) { b3 = (uint32_t)i; break; }
        acc += hist[i];
      }
      uint32_t kth = (bA << 20) | (bB << 8) | b3;
      s_kth = kth;
      s_kth_scaled = key2f(kth) / temp;
    }
    __syncthreads();
    const float kth_scaled = s_kth_scaled;

    // ---- gumbel-argmax over kept candidates (division only here) ----
    float bv = -INFINITY;
    int bi = 0x7FFFFFFF;
    for (int i = tid; i < (int)cnt; i += BLOCK) {
      float sc = key2f(cand_key[i]) / temp;
      if (sc >= kth_scaled) {
        int v = cand_idx[i];
        float g = gumbel_at((uint32_t)r * (uint32_t)V + (uint32_t)v);
        float val = sc + g;
        if (val > bv || (val == bv && v < bi)) { bv = val; bi = v; }
      }
    }
    __syncthreads();
    float* rv = (float*)hist;
    int*   ri = (int*)(hist + BLOCK);
    rv[tid] = bv; ri[tid] = bi;
    __syncthreads();
    for (int s = BLOCK >> 1; s > 0; s >>= 1) {
      if (tid < s) {
        float ov = rv[tid + s]; int oi = ri[tid + s];
        if (ov > rv[tid] || (ov == rv[tid] && oi < ri[tid])) {
          rv[tid] = ov; ri[tid] = oi;
        }
      }
      __syncthreads();
    }
    if (tid == 0) out[r] = ri[0];
    return;
  }

  // ---- fallback (pathological duplicate-heavy rows): global refinement ----
  for (int i = tid; i < NBIN; i += BLOCK) hist[i] = 0u;
  __syncthreads();
  for (int i = tid; i < V; i += BLOCK) {
    uint32_t key = f2key(row[i]);
    if ((key >> 20) == b1) atomicAdd(&hist[(key >> 8) & 0xFFFu], 1u);
  }
  __syncthreads();
  find4096(hist, super, r1, &s_bin, &s_rank);
  const uint32_t b2 = s_bin; const uint32_t r2 = s_rank;
  for (int i = tid; i < 256; i += BLOCK) hist[i] = 0u;
  __syncthreads();
  for (int i = tid; i < V; i += BLOCK) {
    uint32_t key = f2key(row[i]);
    if ((key >> 8) == ((b1 << 12) | b2)) atomicAdd(&hist[key & 0xFFu], 1u);
  }
  __syncthreads();
  if (tid == 0) {
    uint32_t acc = 0; uint32_t b3 = 0;
    for (int i = 255; i >= 0; --i) {
      if (acc + hist[i] >= r2) { b3 = (uint32_t)i; break; }
      acc += hist[i];
    }
    uint32_t kth = (b1 << 20) | (b2 << 8) | b3;
    s_kth = kth;
    s_kth_scaled = key2f(kth) / temp;
  }
  __syncthreads();
  const uint32_t kth_key = s_kth;
  const float kth_scaled = s_kth_scaled;
  uint32_t lo2 = (kth_key >= SLACK) ? (kth_key - SLACK) : 0u;

  float bv = -INFINITY;
  int bi = 0x7FFFFFFF;
  for (int i = tid; i < V; i += BLOCK) {
    float x = row[i];
    uint32_t key = f2key(x);
    if (key >= lo2) {
      float sc = x / temp;
      if (sc >= kth_scaled) {
        float g = gumbel_at((uint32_t)r * (uint32_t)V + (uint32_t)i);
        float val = sc + g;
        if (val > bv || (val == bv && i < bi)) { bv = val; bi = i; }
      }
    }
  }
  __syncthreads();
  float* rv = (float*)hist;
  int*   ri = (int*)(hist + BLOCK);
  rv[tid] = bv; ri[tid] = bi;
  __syncthreads();
  for (int s = BLOCK >> 1; s > 0; s >>= 1) {
    if (tid < s) {
      float ov = rv[tid + s]; int oi = ri[tid + s];
      if (ov > rv[tid] || (ov == rv[tid] && oi < ri[tid])) {
        rv[tid] = ov; ri[tid] = oi;
      }
    }
    __syncthreads();
  }
  if (tid == 0) out[r] = ri[0];
}

extern "C" void kernel_launch(void* const* d_in, const int* in_sizes, int n_in,
                              void* d_out, int out_size, void* d_ws, size_t ws_size,
                              hipStream_t stream) {
  const float* logits = (const float*)d_in[0];
  const float* temps  = (const float*)d_in[1];
  const int*   topk   = (const int*)d_in[2];
  int* out = (int*)d_out;
  const int B = in_sizes[1];           // 256
  const int V = in_sizes[0] / B;       // 128000
  sampler_kernel<<<B, BLOCK, 0, stream>>>(logits, temps, topk, out, B, V);
}

// Round 3
// 50.729 us; speedup vs baseline: 1.8879x; 1.3882x over previous
//
#include <hip/hip_runtime.h>
#include <stdint.h>
#include <math.h>

// ---------------------------------------------------------------------------
// Sampler: temperature-scale -> top-k threshold -> Gumbel-max categorical.
// Exact reproduction of the JAX reference (threefry partitionable, key 42).
//
// R2 structure: single streaming pass collects ALL elements >= SPEC (static
// speculative threshold, float compare only). If count >= K the top-K is
// provably inside the collection; exact kth + filter + gumbel-argmax run on
// the ~800 LDS-resident candidates. Fallback to full histogram algorithm
// (reads warm L3) if the speculation fails -- correctness is distribution-
// independent.
// ---------------------------------------------------------------------------

#define BLOCK 1024
#define NBIN  4096
#define CAP   4096
#define SLACK 64u
#define SPEC_F 2.5f
#define SPEC_KEY 0xC0200000u   // f2key(2.5f)

__device__ __forceinline__ uint32_t rotl32(uint32_t x, uint32_t r) {
  return (x << r) | (x >> (32u - r));
}

// order-preserving map f32 -> u32
__device__ __forceinline__ uint32_t f2key(float x) {
  uint32_t b = __float_as_uint(x);
  return (b & 0x80000000u) ? ~b : (b | 0x80000000u);
}
__device__ __forceinline__ float key2f(uint32_t k) {
  uint32_t b = (k & 0x80000000u) ? (k & 0x7FFFFFFFu) : ~k;
  return __uint_as_float(b);
}

// Threefry-2x32, key = (0, 42)
__device__ __forceinline__ void tf2x32(uint32_t x0, uint32_t x1,
                                       uint32_t &o0, uint32_t &o1) {
  const uint32_t k0 = 0u, k1 = 42u;
  const uint32_t k2 = k0 ^ k1 ^ 0x1BD11BDAu;
  x0 += k0; x1 += k1;
#define TF_R(r) { x0 += x1; x1 = rotl32(x1, (r)); x1 ^= x0; }
  TF_R(13u) TF_R(15u) TF_R(26u) TF_R(6u)
  x0 += k1; x1 += k2 + 1u;
  TF_R(17u) TF_R(29u) TF_R(16u) TF_R(24u)
  x0 += k2; x1 += k0 + 2u;
  TF_R(13u) TF_R(15u) TF_R(26u) TF_R(6u)
  x0 += k0; x1 += k1 + 3u;
  TF_R(17u) TF_R(29u) TF_R(16u) TF_R(24u)
  x0 += k1; x1 += k2 + 4u;
  TF_R(13u) TF_R(15u) TF_R(26u) TF_R(6u)
  x0 += k2; x1 += k0 + 5u;
#undef TF_R
  o0 = x0; o1 = x1;
}

__device__ __forceinline__ float gumbel_at(uint32_t j) {
  uint32_t o0, o1;
  tf2x32(0u, j, o0, o1);
  uint32_t bits = o0 ^ o1;
  float f = __uint_as_float((bits >> 9) | 0x3F800000u) - 1.0f;
  const float TINY = 1.17549435e-38f;
  float u = (f == 0.0f) ? TINY : f;
  return -logf(-logf(u));
}

// descending-rank select over hist[4096]; writes bin and 1-based in-bin rank
__device__ void find4096(uint32_t* hist, uint32_t* super, uint32_t Kt,
                         uint32_t* s_bin, uint32_t* s_rank) {
  const int tid = threadIdx.x;
  if (tid < 64) {
    uint32_t s = 0;
    for (int i = 0; i < 64; ++i) s += hist[tid * 64 + i];
    super[tid] = s;
  }
  __syncthreads();
  if (tid == 0) {
    uint32_t acc = 0; int sb = 0;
    for (int s = 63; s >= 0; --s) {
      if (acc + super[s] >= Kt) { sb = s; break; }
      acc += super[s];
    }
    uint32_t bfound = (uint32_t)(sb * 64);
    for (int i = 63; i >= 0; --i) {
      uint32_t bin = (uint32_t)(sb * 64 + i);
      if (acc + hist[bin] >= Kt) { bfound = bin; break; }
      acc += hist[bin];
    }
    *s_bin = bfound; *s_rank = Kt - acc;
  }
  __syncthreads();
}

// Exact kth-largest key among cand[0:cnt] via 3-level LDS refinement.
// All threads participate; result valid in *s_kth after return.
__device__ void kth_of_cand(const uint32_t* cand_key, uint32_t cnt, uint32_t K,
                            uint32_t* hist, uint32_t* super,
                            uint32_t* s_bin, uint32_t* s_rank, uint32_t* s_kth) {
  const int tid = threadIdx.x;
  for (int i = tid; i < NBIN; i += BLOCK) hist[i] = 0u;
  __syncthreads();
  for (int i = tid; i < (int)cnt; i += BLOCK)
    atomicAdd(&hist[cand_key[i] >> 20], 1u);
  __syncthreads();
  find4096(hist, super, K, s_bin, s_rank);
  const uint32_t bA = *s_bin; const uint32_t rA = *s_rank;

  for (int i = tid; i < NBIN; i += BLOCK) hist[i] = 0u;
  __syncthreads();
  for (int i = tid; i < (int)cnt; i += BLOCK) {
    uint32_t key = cand_key[i];
    if ((key >> 20) == bA) atomicAdd(&hist[(key >> 8) & 0xFFFu], 1u);
  }
  __syncthreads();
  find4096(hist, super, rA, s_bin, s_rank);
  const uint32_t bB = *s_bin; const uint32_t rB = *s_rank;

  for (int i = tid; i < 256; i += BLOCK) hist[i] = 0u;
  __syncthreads();
  for (int i = tid; i < (int)cnt; i += BLOCK) {
    uint32_t key = cand_key[i];
    if ((key >> 8) == ((bA << 12) | bB)) atomicAdd(&hist[key & 0xFFu], 1u);
  }
  __syncthreads();
  if (tid == 0) {
    uint32_t acc = 0; uint32_t b3 = 0;
    for (int i = 255; i >= 0; --i) {
      if (acc + hist[i] >= rB) { b3 = (uint32_t)i; break; }
      acc += hist[i];
    }
    *s_kth = (bA << 20) | (bB << 8) | b3;
  }
  __syncthreads();
}

// final gumbel-argmax over cand survivors + block reduction; writes out[r]
__device__ void gumbel_argmax_cand(const uint32_t* cand_key, const int* cand_idx,
                                   uint32_t cnt, float kth_scaled, float temp,
                                   uint32_t jbase, uint32_t* hist,
                                   int* out, int r) {
  const int tid = threadIdx.x;
  float bv = -INFINITY;
  int bi = 0x7FFFFFFF;
  for (int i = tid; i < (int)cnt; i += BLOCK) {
    float sc = key2f(cand_key[i]) / temp;
    if (sc >= kth_scaled) {
      int v = cand_idx[i];
      float g = gumbel_at(jbase + (uint32_t)v);
      float val = sc + g;
      if (val > bv || (val == bv && v < bi)) { bv = val; bi = v; }
    }
  }
  __syncthreads();
  float* rv = (float*)hist;
  int*   ri = (int*)(hist + BLOCK);
  rv[tid] = bv; ri[tid] = bi;
  __syncthreads();
  for (int s = BLOCK >> 1; s > 0; s >>= 1) {
    if (tid < s) {
      float ov = rv[tid + s]; int oi = ri[tid + s];
      if (ov > rv[tid] || (ov == rv[tid] && oi < ri[tid])) {
        rv[tid] = ov; ri[tid] = oi;
      }
    }
    __syncthreads();
  }
  if (tid == 0) out[r] = ri[0];
}

__global__ __launch_bounds__(BLOCK)
void sampler_kernel(const float* __restrict__ logits,
                    const float* __restrict__ temps,
                    const int* __restrict__ topk_p,
                    int* __restrict__ out, int B, int V) {
  const int r = blockIdx.x;
  const int tid = threadIdx.x;
  const uint32_t K = (uint32_t)(*topk_p);
  const float temp = temps[r];
  const float* row = logits + (size_t)r * (size_t)V;
  const uint32_t jbase = (uint32_t)r * (uint32_t)V;

  __shared__ uint32_t hist[NBIN];
  __shared__ uint32_t super[64];
  __shared__ uint32_t cand_key[CAP];
  __shared__ int      cand_idx[CAP];
  __shared__ uint32_t s_cnt, s_bin, s_rank, s_kth;
  __shared__ float    s_kth_scaled;

  const int n4 = V >> 2;
  const float4* row4 = (const float4*)row;

  // ---- single streaming pass: collect everything >= SPEC_F ----
  if (tid == 0) s_cnt = 0u;
  __syncthreads();
#pragma unroll 4
  for (int i = tid; i < n4; i += BLOCK) {
    float4 x = row4[i];
    if (x.x >= SPEC_F) {
      uint32_t p = atomicAdd(&s_cnt, 1u);
      if (p < CAP) { cand_key[p] = f2key(x.x); cand_idx[p] = (i << 2) + 0; }
    }
    if (x.y >= SPEC_F) {
      uint32_t p = atomicAdd(&s_cnt, 1u);
      if (p < CAP) { cand_key[p] = f2key(x.y); cand_idx[p] = (i << 2) + 1; }
    }
    if (x.z >= SPEC_F) {
      uint32_t p = atomicAdd(&s_cnt, 1u);
      if (p < CAP) { cand_key[p] = f2key(x.z); cand_idx[p] = (i << 2) + 2; }
    }
    if (x.w >= SPEC_F) {
      uint32_t p = atomicAdd(&s_cnt, 1u);
      if (p < CAP) { cand_key[p] = f2key(x.w); cand_idx[p] = (i << 2) + 3; }
    }
  }
  for (int i = (n4 << 2) + tid; i < V; i += BLOCK) {
    float x = row[i];
    if (x >= SPEC_F) {
      uint32_t p = atomicAdd(&s_cnt, 1u);
      if (p < CAP) { cand_key[p] = f2key(x); cand_idx[p] = i; }
    }
  }
  __syncthreads();
  const uint32_t cnt = s_cnt;

  if (cnt >= K && cnt <= CAP) {
    kth_of_cand(cand_key, cnt, K, hist, super, &s_bin, &s_rank, &s_kth);
    const uint32_t kth_key = s_kth;
    if (kth_key >= SPEC_KEY + SLACK) {
      // speculation valid: every element the reference keeps is in cand
      if (tid == 0) s_kth_scaled = key2f(kth_key) / temp;
      __syncthreads();
      gumbel_argmax_cand(cand_key, cand_idx, cnt, s_kth_scaled, temp,
                         jbase, hist, out, r);
      return;
    }
  }

  // ================= fallback: full histogram algorithm (L3-warm) ==========
  for (int i = tid; i < NBIN; i += BLOCK) hist[i] = 0u;
  if (tid == 0) s_cnt = 0u;
  __syncthreads();
  for (int i = tid; i < n4; i += BLOCK) {
    float4 x = row4[i];
    atomicAdd(&hist[f2key(x.x) >> 20], 1u);
    atomicAdd(&hist[f2key(x.y) >> 20], 1u);
    atomicAdd(&hist[f2key(x.z) >> 20], 1u);
    atomicAdd(&hist[f2key(x.w) >> 20], 1u);
  }
  for (int i = (n4 << 2) + tid; i < V; i += BLOCK)
    atomicAdd(&hist[f2key(row[i]) >> 20], 1u);
  __syncthreads();
  find4096(hist, super, K, &s_bin, &s_rank);
  const uint32_t b1 = s_bin;
  const uint32_t r1 = s_rank;

  uint32_t lo = b1 << 20;
  lo = (lo >= SLACK) ? (lo - SLACK) : 0u;
  for (int i = tid; i < n4; i += BLOCK) {
    float4 x = row4[i];
    float s[4] = {x.x, x.y, x.z, x.w};
#pragma unroll
    for (int q = 0; q < 4; ++q) {
      uint32_t key = f2key(s[q]);
      if (key >= lo) {
        uint32_t p = atomicAdd(&s_cnt, 1u);
        if (p < CAP) { cand_key[p] = key; cand_idx[p] = (i << 2) + q; }
      }
    }
  }
  for (int i = (n4 << 2) + tid; i < V; i += BLOCK) {
    uint32_t key = f2key(row[i]);
    if (key >= lo) {
      uint32_t p = atomicAdd(&s_cnt, 1u);
      if (p < CAP) { cand_key[p] = key; cand_idx[p] = i; }
    }
  }
  __syncthreads();
  const uint32_t cnt2 = s_cnt;

  if (cnt2 <= CAP) {
    kth_of_cand(cand_key, cnt2, K, hist, super, &s_bin, &s_rank, &s_kth);
    if (tid == 0) s_kth_scaled = key2f(s_kth) / temp;
    __syncthreads();
    gumbel_argmax_cand(cand_key, cand_idx, cnt2, s_kth_scaled, temp,
                       jbase, hist, out, r);
    return;
  }

  // ---- pathological duplicate-heavy rows: refine from global memory ----
  for (int i = tid; i < NBIN; i += BLOCK) hist[i] = 0u;
  __syncthreads();
  for (int i = tid; i < V; i += BLOCK) {
    uint32_t key = f2key(row[i]);
    if ((key >> 20) == b1) atomicAdd(&hist[(key >> 8) & 0xFFFu], 1u);
  }
  __syncthreads();
  find4096(hist, super, r1, &s_bin, &s_rank);
  const uint32_t b2 = s_bin; const uint32_t r2 = s_rank;
  for (int i = tid; i < 256; i += BLOCK) hist[i] = 0u;
  __syncthreads();
  for (int i = tid; i < V; i += BLOCK) {
    uint32_t key = f2key(row[i]);
    if ((key >> 8) == ((b1 << 12) | b2)) atomicAdd(&hist[key & 0xFFu], 1u);
  }
  __syncthreads();
  if (tid == 0) {
    uint32_t acc = 0; uint32_t b3 = 0;
    for (int i = 255; i >= 0; --i) {
      if (acc + hist[i] >= r2) { b3 = (uint32_t)i; break; }
      acc += hist[i];
    }
    uint32_t kth = (b1 << 20) | (b2 << 8) | b3;
    s_kth = kth;
    s_kth_scaled = key2f(kth) / temp;
  }
  __syncthreads();
  const uint32_t kth_key = s_kth;
  const float kth_scaled = s_kth_scaled;
  uint32_t lo2 = (kth_key >= SLACK) ? (kth_key - SLACK) : 0u;

  float bv = -INFINITY;
  int bi = 0x7FFFFFFF;
  for (int i = tid; i < V; i += BLOCK) {
    float x = row[i];
    uint32_t key = f2key(x);
    if (key >= lo2) {
      float sc = x / temp;
      if (sc >= kth_scaled) {
        float g = gumbel_at(jbase + (uint32_t)i);
        float val = sc + g;
        if (val > bv || (val == bv && i < bi)) { bv = val; bi = i; }
      }
    }
  }
  __syncthreads();
  float* rv = (float*)hist;
  int*   ri = (int*)(hist + BLOCK);
  rv[tid] = bv; ri[tid] = bi;
  __syncthreads();
  for (int s = BLOCK >> 1; s > 0; s >>= 1) {
    if (tid < s) {
      float ov = rv[tid + s]; int oi = ri[tid + s];
      if (ov > rv[tid] || (ov == rv[tid] && oi < ri[tid])) {
        rv[tid] = ov; ri[tid] = oi;
      }
    }
    __syncthreads();
  }
  if (tid == 0) out[r] = ri[0];
}

extern "C" void kernel_launch(void* const* d_in, const int* in_sizes, int n_in,
                              void* d_out, int out_size, void* d_ws, size_t ws_size,
                              hipStream_t stream) {
  const float* logits = (const float*)d_in[0];
  const float* temps  = (const float*)d_in[1];
  const int*   topk   = (const int*)d_in[2];
  int* out = (int*)d_out;
  const int B = in_sizes[1];           // 256
  const int V = in_sizes[0] / B;       // 128000
  sampler_kernel<<<B, BLOCK, 0, stream>>>(logits, temps, topk, out, B, V);
}